// Round 15
// baseline (209.514 us; speedup 1.0000x reference)
//
#include <hip/hip_runtime.h>
#include <cstdint>
#include <cstddef>

#define N 8192
#define D 128
#define KNN 20
#define NC 10
#define CAPB 448          // max survivor entries per row (k_sel2 register budget: 7*64)
#define SLOTS 16          // per-pool LDS survivor slots per block (lambda~2.3, P(>16)~1e-10)
#define ZTH 2.1f          // threshold z-score (expected ~146 survivors/row)
#define NW (N / 32)       // bitmap words per row
#define NT 64             // 128-wide tiles per dim
#define NBLK (NT * (NT + 1) / 2)   // 2080 upper-triangle tiles
constexpr float EPS = 1e-10f;

typedef __attribute__((ext_vector_type(8))) short short8;
typedef __attribute__((ext_vector_type(4))) float f32x4;

__device__ inline unsigned short f32_to_bf16_rne(float x) {
    unsigned u = __float_as_uint(x);
    unsigned r = u + 0x7FFFu + ((u >> 16) & 1u);
    return (unsigned short)(r >> 16);
}
__device__ inline float bf16_to_f32(unsigned short h) {
    return __uint_as_float((unsigned)h << 16);
}
__device__ inline unsigned long long pack_key(float d, int j) {
    return ((unsigned long long)__float_as_uint(d) << 14) | (unsigned long long)(j + 1);
}

// ---------------- K1: fused sqnorm + bf16 hi/lo split + workspace zeroing ------
__global__ void k_prep(const float* __restrict__ X, unsigned short* __restrict__ Xhi,
                       unsigned short* __restrict__ Xlo, float* __restrict__ sq,
                       uint4* __restrict__ bits4, uint4* __restrict__ bitsT4,
                       unsigned* __restrict__ zw, int nzw) {
    int row = blockIdx.x, t = threadIdx.x;      // 64 lanes
    const float2* X2 = (const float2*)(X + (size_t)row * D);
    float2 a = X2[t];
    ushort2 h, l;
    h.x = f32_to_bf16_rne(a.x); l.x = f32_to_bf16_rne(a.x - bf16_to_f32(h.x));
    h.y = f32_to_bf16_rne(a.y); l.y = f32_to_bf16_rne(a.y - bf16_to_f32(h.y));
    *(ushort2*)&Xhi[(size_t)row * D + 2 * t] = h;
    *(ushort2*)&Xlo[(size_t)row * D + 2 * t] = l;
    int tid = row * 64 + t;
    bits4[tid]  = make_uint4(0u, 0u, 0u, 0u);
    bitsT4[tid] = make_uint4(0u, 0u, 0u, 0u);
    if (tid < nzw) zw[tid] = 0u;
    float s = a.x * a.x + a.y * a.y;
    #pragma unroll
    for (int off = 32; off; off >>= 1) s += __shfl_down(s, off, 64);
    if (t == 0) sq[row] = s;
}

// ---------------- K2b: data moments (col sums, sum sq, sum sq^2) ----------------
__global__ __launch_bounds__(128) void k_moments(const float* __restrict__ X,
                                                 const float* __restrict__ sq,
                                                 float* __restrict__ m1,
                                                 float* __restrict__ msc) {
    int b = blockIdx.x, t = threadIdx.x;        // 512 blocks x 128 threads, 16 rows each
    int r0 = b * 16;
    float s1 = 0.f;
    #pragma unroll
    for (int r = 0; r < 16; ++r) s1 += X[(size_t)(r0 + r) * D + t];
    atomicAdd(&m1[t], s1);
    if (t < 16) {
        float s = sq[r0 + t];
        float ss1 = s, ss2 = s * s;
        #pragma unroll
        for (int off = 8; off; off >>= 1) {
            ss1 += __shfl_down(ss1, off, 64);
            ss2 += __shfl_down(ss2, off, 64);
        }
        if (t == 0) { atomicAdd(&msc[0], ss1); atomicAdd(&msc[1], ss2); }
    }
}

// ---------------- K2c: per-row analytic survivor threshold ----------------
__global__ void k_thresh(const float* __restrict__ X, const float* __restrict__ sq,
                         const float* __restrict__ m1, const float* __restrict__ msc,
                         float* __restrict__ T) {
    int row = blockIdx.x, lane = threadIdx.x;   // 64 lanes
    const float2* X2 = (const float2*)(X + (size_t)row * D);
    const float2* M2 = (const float2*)m1;
    float2 a = X2[lane], m = M2[lane];
    float dotp = a.x * m.x + a.y * m.y;
    #pragma unroll
    for (int off = 32; off; off >>= 1) dotp += __shfl_down(dotp, off, 64);
    if (lane == 0) {
        const float invN = 1.f / N;
        float Esq   = msc[0] * invN;
        float Esq2  = msc[1] * invN;
        float varSq = fmaxf(Esq2 - Esq * Esq, 0.f);
        float s  = sq[row];
        float mu = s + Esq - 2.f * dotp * invN;
        float var = varSq + 4.f * s;
        T[row] = mu - ZTH * sqrtf(var);
    }
}

// ---------------- K3: fused MFMA distance + filter, upper-triangle ----------
// R13 structure + T14 async-STAGE split for the A-tile: A for kc+1 is
// prefetched into 4 uint4 registers DURING the MFMA phase of kc, so at the
// next barrier only the ds_write remains (global latency hidden). +16 VGPR
// -> 164 <= 170/wave at 3 blocks/CU (B not prefetched: 180 would spill,
// R11/R12 lesson). Staged values identical -> d2 bit-identical.
#define ASTRIDE 40   // bf16 elems per LDS row (32 data + 8 pad); 80 B, 16B-aligned
struct StageS {
    unsigned short Ahi[128 * ASTRIDE];
    unsigned short Alo[128 * ASTRIDE];
    unsigned short Bhi[128 * ASTRIDE];
    unsigned short Blo[128 * ASTRIDE];
};
struct EpiS {
    unsigned long long slots[256 * SLOTS];   // 32 KB
    unsigned rc[256];
    unsigned rbase[256];
};
__global__ __launch_bounds__(256, 3) void k_distf3(
        const unsigned short* __restrict__ Xhi, const unsigned short* __restrict__ Xlo,
        const float* __restrict__ sqn, const float* __restrict__ Tthr,
        int* __restrict__ cnt, unsigned long long* __restrict__ rowbuf, int capb) {
    // linear block -> upper-triangle tile (by <= bx)
    int rem = blockIdx.x, by = 0;
    while (rem >= NT - by) { rem -= NT - by; ++by; }
    const int bx = by + rem;

    __shared__ alignas(16) union { StageS s; EpiS e; } U;

    const int t    = threadIdx.x;
    const int lane = t & 63;
    const int w    = t >> 6;
    const int wr   = w >> 1;          // 0..1 : 64-row half
    const int wc   = w & 1;           // 0..1 : 64-col half
    const int lrow = lane & 15;       // fragment row within 16
    const int lkg  = lane >> 4;       // 0..3 : k-group (8 bf16 each)

    const int rowTile = by * 128;
    const int colTile = bx * 128;

    f32x4 acc[4][4];
    #pragma unroll
    for (int i = 0; i < 4; ++i)
        #pragma unroll
        for (int j = 0; j < 4; ++j) acc[i][j] = (f32x4){0.f, 0.f, 0.f, 0.f};

    // prologue: prefetch A-tile for kc=0 into registers
    uint4 pAhi[2], pAlo[2];                     // static-indexed only (rule #20)
    #pragma unroll
    for (int p = 0; p < 2; ++p) {
        int u = t + 256 * p, r = u >> 2, c = u & 3;
        size_t g = (size_t)(rowTile + r) * 128 + c * 8;
        pAhi[p] = *(const uint4*)&Xhi[g];
        pAlo[p] = *(const uint4*)&Xlo[g];
    }

    for (int kc = 0; kc < 4; ++kc) {            // four K-chunks of 32
        const int kb = kc * 32;
        __syncthreads();
        #pragma unroll
        for (int p = 0; p < 2; ++p) {           // A: write-late from regs
            int u = t + 256 * p, r = u >> 2, c = u & 3;
            *(uint4*)&U.s.Ahi[r * ASTRIDE + c * 8] = pAhi[p];
            *(uint4*)&U.s.Alo[r * ASTRIDE + c * 8] = pAlo[p];
        }
        #pragma unroll
        for (int p = 0; p < 2; ++p) {           // B: direct stage (latency exposed)
            int u = t + 256 * p, r = u >> 2, c = u & 3;
            size_t g = (size_t)(colTile + r) * 128 + kb + c * 8;
            *(uint4*)&U.s.Bhi[r * ASTRIDE + c * 8] = *(const uint4*)&Xhi[g];
            *(uint4*)&U.s.Blo[r * ASTRIDE + c * 8] = *(const uint4*)&Xlo[g];
        }
        __syncthreads();

        if (kc < 3) {                           // A: issue-early for kc+1
            #pragma unroll
            for (int p = 0; p < 2; ++p) {
                int u = t + 256 * p, r = u >> 2, c = u & 3;
                size_t g = (size_t)(rowTile + r) * 128 + (kb + 32) + c * 8;
                pAhi[p] = *(const uint4*)&Xhi[g];
                pAlo[p] = *(const uint4*)&Xlo[g];
            }
        }

        short8 a[4], bh[4], bl[4];
        #pragma unroll
        for (int i = 0; i < 4; ++i)
            a[i] = *(const short8*)&U.s.Ahi[(wr * 64 + 16 * i + lrow) * ASTRIDE + lkg * 8];
        #pragma unroll
        for (int j = 0; j < 4; ++j)
            bh[j] = *(const short8*)&U.s.Bhi[(wc * 64 + 16 * j + lrow) * ASTRIDE + lkg * 8];
        #pragma unroll
        for (int j = 0; j < 4; ++j)
            bl[j] = *(const short8*)&U.s.Blo[(wc * 64 + 16 * j + lrow) * ASTRIDE + lkg * 8];
        // pass 1: hi . hi
        #pragma unroll
        for (int i = 0; i < 4; ++i)
            #pragma unroll
            for (int j = 0; j < 4; ++j)
                acc[i][j] = __builtin_amdgcn_mfma_f32_16x16x32_bf16(a[i], bh[j], acc[i][j], 0, 0, 0);
        // pass 2: hi . lo
        #pragma unroll
        for (int i = 0; i < 4; ++i)
            #pragma unroll
            for (int j = 0; j < 4; ++j)
                acc[i][j] = __builtin_amdgcn_mfma_f32_16x16x32_bf16(a[i], bl[j], acc[i][j], 0, 0, 0);
        // pass 3: lo . hi (a reload; bh reused from regs)
        #pragma unroll
        for (int i = 0; i < 4; ++i)
            a[i] = *(const short8*)&U.s.Alo[(wr * 64 + 16 * i + lrow) * ASTRIDE + lkg * 8];
        #pragma unroll
        for (int i = 0; i < 4; ++i)
            #pragma unroll
            for (int j = 0; j < 4; ++j)
                acc[i][j] = __builtin_amdgcn_mfma_f32_16x16x32_bf16(a[i], bh[j], acc[i][j], 0, 0, 0);
    }

    // ---- epilogue: dual-pool LDS survivor aggregation, batched atomics ----
    __syncthreads();                            // staging LDS dead; overlay epilogue
    U.e.rc[t] = 0;
    __syncthreads();

    // C/D layout col=lane&15, row=(lane>>4)*4+reg  [m89/m91]
    float sqb[4], Tb[4]; int gcol[4], lcol[4];
    #pragma unroll
    for (int j = 0; j < 4; ++j) {
        lcol[j] = wc * 64 + 16 * j + lrow;
        gcol[j] = colTile + lcol[j];
        sqb[j]  = sqn[gcol[j]];
        Tb[j]   = Tthr[gcol[j]];
    }
    const int giBase = rowTile + wr * 64 + lkg * 4;
    float sav[4][4];                            // static-indexed, never address-taken
    #pragma unroll
    for (int i = 0; i < 4; ++i)
        #pragma unroll
        for (int q = 0; q < 4; ++q)
            sav[i][q] = sqn[giBase + 16 * i + q];

    float dall[4][4][4];                        // [i][q][j]; static-indexed only

    // forward: compute all 64 d once; one LDS atomic per (i,q) group
    #pragma unroll
    for (int i = 0; i < 4; ++i) {
        #pragma unroll
        for (int q = 0; q < 4; ++q) {
            const int gi = giBase + 16 * i + q;
            const int lr = gi - rowTile;
            const float Ti = Tthr[gi];
            unsigned m4 = 0;
            #pragma unroll
            for (int j = 0; j < 4; ++j) {
                float d = fmaxf(fmaf(-2.f, acc[i][j][q], sav[i][q] + sqb[j]), 0.f);
                dall[i][q][j] = d;
                bool c = (gcol[j] >= gi) && (d < Ti);
                m4 |= (unsigned)c << j;
            }
            if (m4) {
                unsigned o = atomicAdd(&U.e.rc[lr], (unsigned)__popc(m4));
                #pragma unroll
                for (int j = 0; j < 4; ++j)
                    if (m4 & (1u << j)) {
                        if (o < SLOTS)
                            U.e.slots[lr * SLOTS + o] = pack_key(dall[i][q][j], gcol[j]);
                        ++o;
                    }
            }
        }
    }
    // transpose: reuse dall; one LDS atomic per col j
    #pragma unroll
    for (int j = 0; j < 4; ++j) {
        const int pool = 128 + lcol[j];
        const float Tbj = Tb[j];
        const int gj = gcol[j];
        unsigned m16 = 0;
        #pragma unroll
        for (int i = 0; i < 4; ++i)
            #pragma unroll
            for (int q = 0; q < 4; ++q) {
                bool c = (gj > giBase + 16 * i + q) && (dall[i][q][j] < Tbj);
                m16 |= (unsigned)c << (i * 4 + q);
            }
        if (m16) {
            unsigned o = atomicAdd(&U.e.rc[pool], (unsigned)__popc(m16));
            #pragma unroll
            for (int i = 0; i < 4; ++i)
                #pragma unroll
                for (int q = 0; q < 4; ++q)
                    if (m16 & (1u << (i * 4 + q))) {
                        if (o < SLOTS)
                            U.e.slots[pool * SLOTS + o] =
                                pack_key(dall[i][q][j], giBase + 16 * i + q);
                        ++o;
                    }
        }
    }

    __syncthreads();
    {                                           // one global atomic per pool
        unsigned nr = U.e.rc[t];
        int grow = (t < 128) ? (rowTile + t) : (colTile + (t - 128));
        if (nr > SLOTS) {                       // ~never: force exact fallback
            atomicAdd(&cnt[grow], capb + 1);
            U.e.rbase[t] = 0xFFFFFFFFu;
        } else if (nr > 0) {
            U.e.rbase[t] = (unsigned)atomicAdd(&cnt[grow], (int)nr);
        } else {
            U.e.rbase[t] = 0;
        }
    }
    __syncthreads();
    #pragma unroll
    for (int it = 0; it < (256 * SLOTS) / 256; ++it) {   // coalesced flush
        int idx = t + 256 * it;
        int r = idx >> 4, s = idx & 15;
        unsigned nr = U.e.rc[r], base = U.e.rbase[r];
        if ((unsigned)s < min(nr, (unsigned)SLOTS) && base != 0xFFFFFFFFu) {
            unsigned pos = base + (unsigned)s;
            int grow = (r < 128) ? (rowTile + r) : (colTile + (r - 128));
            if (pos < (unsigned)capb)
                rowbuf[(size_t)grow * capb + pos] = U.e.slots[r * SLOTS + s];
        }
    }
}

// ---------------- K4: exact top-20 from survivor buffer (+ dual bitmap set) ----
__global__ __launch_bounds__(64) void k_sel2(const unsigned long long* __restrict__ rowbuf,
                                             const int* __restrict__ cnt,
                                             int* __restrict__ knn_idx,
                                             float* __restrict__ density,
                                             unsigned* __restrict__ bits,
                                             unsigned* __restrict__ bitsT,
                                             int* __restrict__ flagged,
                                             int* __restrict__ nflag, int capb) {
    __shared__ int nb[KNN];
    int row = blockIdx.x, t = threadIdx.x;
    int n = cnt[row];
    if (n < KNN || n > capb) {                  // model miss: exact fallback handles it
        if (t == 0) { int p = atomicAdd(nflag, 1); flagged[p] = row; }
        return;
    }
    const unsigned long long* rb = rowbuf + (size_t)row * capb;
    unsigned long long v[7];                    // 7*64 = 448 >= capb
    #pragma unroll
    for (int k = 0; k < 7; ++k) { int idx = t + 64 * k; v[k] = idx < n ? rb[idx] : ~0ull; }
    unsigned long long last = 0ull;
    float sumd = 0.f;
    for (int r = 0; r < KNN; ++r) {
        unsigned long long m = ~0ull;
        #pragma unroll
        for (int k = 0; k < 7; ++k) if (v[k] > last && v[k] < m) m = v[k];
        #pragma unroll
        for (int off = 32; off; off >>= 1) {
            unsigned long long o = __shfl_down(m, off, 64);
            if (o < m) m = o;
        }
        m = __shfl(m, 0, 64);
        last = m;
        if (t == 0) {
            int j = (int)(m & 16383ull) - 1;
            if (j < 0) j = 0; if (j >= N) j = N - 1;
            knn_idx[(size_t)row * KNN + r] = j;
            nb[r] = j;
            sumd += sqrtf(__uint_as_float((unsigned)(m >> 14)));
        }
    }
    if (t == 0) density[row] = 1.f / (sumd * (1.f / KNN) + EPS);
    __syncthreads();
    if (t < KNN) {
        int j = nb[t];
        atomicOr(&bits[(size_t)row * NW + (j >> 5)], 1u << (j & 31));
        atomicOr(&bitsT[(size_t)j * NW + (row >> 5)], 1u << (row & 31));  // fire-and-forget
    }
}

// ---------------- K4b: exact fp32 brute-force fallback for flagged rows -------
__global__ __launch_bounds__(256) void k_fallback(const float* __restrict__ X,
                                                  const float* __restrict__ sq,
                                                  const int* __restrict__ nflag,
                                                  const int* __restrict__ flagged,
                                                  int* __restrict__ knn_idx,
                                                  float* __restrict__ density,
                                                  unsigned* __restrict__ bits,
                                                  unsigned* __restrict__ bitsT) {
    __shared__ float xr[D];
    __shared__ unsigned long long red[256];
    __shared__ int nbf[KNN];
    int t = threadIdx.x;
    int nf = *nflag;
    for (int f = blockIdx.x; f < nf; f += gridDim.x) {
        int row = flagged[f];
        __syncthreads();
        if (t < D) xr[t] = X[(size_t)row * D + t];
        __syncthreads();
        float sqr = sq[row];
        unsigned long long keys[32];
        for (int i = 0; i < 32; ++i) {
            int col = t + 256 * i;
            const float4* cp = (const float4*)(X + (size_t)col * D);
            float dot = 0.f;
            #pragma unroll
            for (int d4 = 0; d4 < 32; ++d4) {
                float4 c = cp[d4];
                float4 x = *(const float4*)&xr[d4 * 4];
                dot = fmaf(c.x, x.x, dot); dot = fmaf(c.y, x.y, dot);
                dot = fmaf(c.z, x.z, dot); dot = fmaf(c.w, x.w, dot);
            }
            float d2v = fmaxf(sqr + sq[col] - 2.f * dot, 0.f);
            keys[i] = pack_key(d2v, col);
        }
        unsigned long long last = 0ull;
        float sumd = 0.f;
        for (int r = 0; r < KNN; ++r) {
            unsigned long long m = ~0ull;
            #pragma unroll
            for (int i = 0; i < 32; ++i) if (keys[i] > last && keys[i] < m) m = keys[i];
            red[t] = m; __syncthreads();
            for (int s = 128; s; s >>= 1) {
                if (t < s && red[t + s] < red[t]) red[t] = red[t + s];
                __syncthreads();
            }
            m = red[0]; __syncthreads();
            last = m;
            if (t == 0) {
                int j = (int)(m & 16383ull) - 1;
                if (j < 0) j = 0; if (j >= N) j = N - 1;
                knn_idx[(size_t)row * KNN + r] = j;
                nbf[r] = j;
                sumd += sqrtf(__uint_as_float((unsigned)(m >> 14)));
            }
        }
        if (t == 0) density[row] = 1.f / (sumd * (1.f / KNN) + EPS);
        __syncthreads();
        if (t < KNN) {
            int j = nbf[t];
            atomicOr(&bits[(size_t)row * NW + (j >> 5)], 1u << (j & 31));
            atomicOr(&bitsT[(size_t)j * NW + (row >> 5)], 1u << (row & 31));
        }
    }
}

// ---------------- K5: row-owned influence sums + final outputs (ZERO atomics) --
// numer/cnt per row from knn + (bitsT & ~bits); then lane 0 computes the
// score, OOD flag, and class pred directly (k_final folded in).
__global__ __launch_bounds__(256) void k_rev2(const int* __restrict__ knn_idx,
                                              const float* __restrict__ density,
                                              const unsigned* __restrict__ bits,
                                              const unsigned* __restrict__ bitsT,
                                              const float* __restrict__ logits,
                                              float* __restrict__ out) {
    int t = threadIdx.x & 63;
    int row = blockIdx.x * 4 + (threadIdx.x >> 6);
    float s = (t < KNN) ? density[knn_idx[(size_t)row * KNN + t]] : 0.f;
    int c = 0;
    const unsigned* br = bits  + (size_t)row * NW;
    const unsigned* tr = bitsT + (size_t)row * NW;
    #pragma unroll
    for (int w_ = 0; w_ < 4; ++w_) {
        int w = t + 64 * w_;
        unsigned u = tr[w] & ~br[w];
        c += __popc(u);
        while (u) {
            int b = __ffs(u) - 1;
            u &= u - 1;
            s += density[w * 32 + b];
        }
    }
    #pragma unroll
    for (int off = 32; off; off >>= 1) {
        s += __shfl_down(s, off, 64);
        c += __shfl_down(c, off, 64);
    }
    if (t == 0) {
        float cf    = fmaxf((float)(KNN + c), 1.f);
        float avg   = s / cf;
        float dens  = density[row];
        float score = -(dens / (avg + EPS));
        out[row] = score;
        bool flag = score < -0.5f;
        out[N + row] = flag ? 1.f : 0.f;
        const float* lg = logits + (size_t)row * NC;
        float best = lg[0]; int bi = 0;
        #pragma unroll
        for (int k = 1; k < NC; ++k) { float x = lg[k]; if (x > best) { best = x; bi = k; } }
        out[2 * N + row] = flag ? -1.f : (float)bi;
    }
}

extern "C" void kernel_launch(void* const* d_in, const int* in_sizes, int n_in,
                              void* d_out, int out_size, void* d_ws, size_t ws_size,
                              hipStream_t stream) {
    const float* X      = (const float*)d_in[0];
    const float* logits = (const float*)d_in[1];
    float* out = (float*)d_out;

    char* w = (char*)d_ws;
    auto alloc = [&](size_t bytes) { char* p = w; w += (bytes + 255) & ~(size_t)255; return p; };
    float* sq      = (float*)alloc((size_t)N * 4);
    float* density = (float*)alloc((size_t)N * 4);
    int*   knn     = (int*)alloc((size_t)N * KNN * 4);
    unsigned short* Xhi = (unsigned short*)alloc((size_t)N * D * 2);
    unsigned short* Xlo = (unsigned short*)alloc((size_t)N * D * 2);
    float* Tthr    = (float*)alloc((size_t)N * 4);
    int*   flagged = (int*)alloc((size_t)N * 4);
    // contiguous zero region (zeroed by k_prep): cnt + nflag + m1
    char* zbase    = w;
    int*   cnt     = (int*)alloc((size_t)N * 4);
    int*   nflag   = (int*)alloc(256);
    float* m1      = (float*)alloc((size_t)(D + 2) * 4);
    int nzw = (int)((size_t)(w - zbase) / 4);   // ~8.5K words << 512K prep threads
    unsigned* bits  = (unsigned*)alloc((size_t)N * NW * 4);   // 8 MB forward bitmap
    unsigned* bitsT = (unsigned*)alloc((size_t)N * NW * 4);   // 8 MB transpose bitmap

    size_t used  = (size_t)(w - (char*)d_ws);
    size_t avail = ws_size > used ? ws_size - used : 0;
    int capb = (int)(avail / ((size_t)N * 8));
    if (capb > CAPB) capb = CAPB;
    if (capb < 1) capb = 1;                     // degenerate: all rows -> exact fallback
    unsigned long long* rowbuf = (unsigned long long*)alloc((size_t)N * capb * 8);

    k_prep   <<<N, 64, 0, stream>>>(X, Xhi, Xlo, sq, (uint4*)bits, (uint4*)bitsT,
                                    (unsigned*)zbase, nzw);
    k_moments<<<512, 128, 0, stream>>>(X, sq, m1, m1 + D);
    k_thresh <<<N, 64, 0, stream>>>(X, sq, m1, m1 + D, Tthr);

    k_distf3 <<<NBLK, 256, 0, stream>>>(Xhi, Xlo, sq, Tthr, cnt, rowbuf, capb);

    k_sel2    <<<N, 64, 0, stream>>>(rowbuf, cnt, knn, density, bits, bitsT,
                                     flagged, nflag, capb);
    k_fallback<<<64, 256, 0, stream>>>(X, sq, nflag, flagged, knn, density, bits, bitsT);

    k_rev2   <<<N / 4, 256, 0, stream>>>(knn, density, bits, bitsT, logits, out);
}

// Round 16
// 183.876 us; speedup vs baseline: 1.1394x; 1.1394x over previous
//
#include <hip/hip_runtime.h>
#include <cstdint>
#include <cstddef>

#define N 8192
#define D 128
#define KNN 20
#define NC 10
#define CAPB 448          // max survivor entries per row (k_sel2 register budget: 7*64)
#define SLOTS 16          // per-pool LDS survivor slots per block (lambda~2.3, P(>16)~1e-10)
#define ZTH 2.1f          // threshold z-score (expected ~146 survivors/row)
#define NW (N / 32)       // bitmap words per row
#define NT 64             // 128-wide tiles per dim
#define NBLK (NT * (NT + 1) / 2)   // 2080 upper-triangle tiles
constexpr float EPS = 1e-10f;

typedef __attribute__((ext_vector_type(8))) short short8;
typedef __attribute__((ext_vector_type(4))) float f32x4;

__device__ inline unsigned short f32_to_bf16_rne(float x) {
    unsigned u = __float_as_uint(x);
    unsigned r = u + 0x7FFFu + ((u >> 16) & 1u);
    return (unsigned short)(r >> 16);
}
__device__ inline float bf16_to_f32(unsigned short h) {
    return __uint_as_float((unsigned)h << 16);
}
__device__ inline unsigned long long pack_key(float d, int j) {
    return ((unsigned long long)__float_as_uint(d) << 14) | (unsigned long long)(j + 1);
}

// ---------------- K1: fused sqnorm + bf16 hi/lo split + workspace zeroing ------
__global__ void k_prep(const float* __restrict__ X, unsigned short* __restrict__ Xhi,
                       unsigned short* __restrict__ Xlo, float* __restrict__ sq,
                       uint4* __restrict__ bits4, uint4* __restrict__ bitsT4,
                       unsigned* __restrict__ zw, int nzw) {
    int row = blockIdx.x, t = threadIdx.x;      // 64 lanes
    const float2* X2 = (const float2*)(X + (size_t)row * D);
    float2 a = X2[t];
    ushort2 h, l;
    h.x = f32_to_bf16_rne(a.x); l.x = f32_to_bf16_rne(a.x - bf16_to_f32(h.x));
    h.y = f32_to_bf16_rne(a.y); l.y = f32_to_bf16_rne(a.y - bf16_to_f32(h.y));
    *(ushort2*)&Xhi[(size_t)row * D + 2 * t] = h;
    *(ushort2*)&Xlo[(size_t)row * D + 2 * t] = l;
    int tid = row * 64 + t;
    bits4[tid]  = make_uint4(0u, 0u, 0u, 0u);
    bitsT4[tid] = make_uint4(0u, 0u, 0u, 0u);
    if (tid < nzw) zw[tid] = 0u;
    float s = a.x * a.x + a.y * a.y;
    #pragma unroll
    for (int off = 32; off; off >>= 1) s += __shfl_down(s, off, 64);
    if (t == 0) sq[row] = s;
}

// ---------------- K2b: data moments (col sums, sum sq, sum sq^2) ----------------
__global__ __launch_bounds__(128) void k_moments(const float* __restrict__ X,
                                                 const float* __restrict__ sq,
                                                 float* __restrict__ m1,
                                                 float* __restrict__ msc) {
    int b = blockIdx.x, t = threadIdx.x;        // 512 blocks x 128 threads, 16 rows each
    int r0 = b * 16;
    float s1 = 0.f;
    #pragma unroll
    for (int r = 0; r < 16; ++r) s1 += X[(size_t)(r0 + r) * D + t];
    atomicAdd(&m1[t], s1);
    if (t < 16) {
        float s = sq[r0 + t];
        float ss1 = s, ss2 = s * s;
        #pragma unroll
        for (int off = 8; off; off >>= 1) {
            ss1 += __shfl_down(ss1, off, 64);
            ss2 += __shfl_down(ss2, off, 64);
        }
        if (t == 0) { atomicAdd(&msc[0], ss1); atomicAdd(&msc[1], ss2); }
    }
}

// ---------------- K2c: per-row analytic survivor threshold ----------------
__global__ void k_thresh(const float* __restrict__ X, const float* __restrict__ sq,
                         const float* __restrict__ m1, const float* __restrict__ msc,
                         float* __restrict__ T) {
    int row = blockIdx.x, lane = threadIdx.x;   // 64 lanes
    const float2* X2 = (const float2*)(X + (size_t)row * D);
    const float2* M2 = (const float2*)m1;
    float2 a = X2[lane], m = M2[lane];
    float dotp = a.x * m.x + a.y * m.y;
    #pragma unroll
    for (int off = 32; off; off >>= 1) dotp += __shfl_down(dotp, off, 64);
    if (lane == 0) {
        const float invN = 1.f / N;
        float Esq   = msc[0] * invN;
        float Esq2  = msc[1] * invN;
        float varSq = fmaxf(Esq2 - Esq * Esq, 0.f);
        float s  = sq[row];
        float mu = s + Esq - 2.f * dotp * invN;
        float var = varSq + 4.f * s;
        T[row] = mu - ZTH * sqrtf(var);
    }
}

// ---------------- K3: fused MFMA distance + filter, upper-triangle ----------
// R13/R14-verified optimum (68.3 us, no spill) — byte-identical. R15 lesson:
// the register budget here is SATURATED (84 arch + 64 AGPR + ~20 temps);
// any added live state across the MFMA phase (prefetch regs) spills to
// scratch (WRITE 18->123 MB). Do not add prefetch/caching to this kernel.
#define ASTRIDE 40   // bf16 elems per LDS row (32 data + 8 pad); 80 B, 16B-aligned
struct StageS {
    unsigned short Ahi[128 * ASTRIDE];
    unsigned short Alo[128 * ASTRIDE];
    unsigned short Bhi[128 * ASTRIDE];
    unsigned short Blo[128 * ASTRIDE];
};
struct EpiS {
    unsigned long long slots[256 * SLOTS];   // 32 KB
    unsigned rc[256];
    unsigned rbase[256];
};
__global__ __launch_bounds__(256, 3) void k_distf3(
        const unsigned short* __restrict__ Xhi, const unsigned short* __restrict__ Xlo,
        const float* __restrict__ sqn, const float* __restrict__ Tthr,
        int* __restrict__ cnt, unsigned long long* __restrict__ rowbuf, int capb) {
    // linear block -> upper-triangle tile (by <= bx)
    int rem = blockIdx.x, by = 0;
    while (rem >= NT - by) { rem -= NT - by; ++by; }
    const int bx = by + rem;

    __shared__ alignas(16) union { StageS s; EpiS e; } U;

    const int t    = threadIdx.x;
    const int lane = t & 63;
    const int w    = t >> 6;
    const int wr   = w >> 1;          // 0..1 : 64-row half
    const int wc   = w & 1;           // 0..1 : 64-col half
    const int lrow = lane & 15;       // fragment row within 16
    const int lkg  = lane >> 4;       // 0..3 : k-group (8 bf16 each)

    const int rowTile = by * 128;
    const int colTile = bx * 128;

    f32x4 acc[4][4];
    #pragma unroll
    for (int i = 0; i < 4; ++i)
        #pragma unroll
        for (int j = 0; j < 4; ++j) acc[i][j] = (f32x4){0.f, 0.f, 0.f, 0.f};

    for (int kc = 0; kc < 4; ++kc) {            // four K-chunks of 32
        const int kb = kc * 32;
        __syncthreads();
        #pragma unroll
        for (int p = 0; p < 2; ++p) {           // stage A (128 rows)
            int u = t + 256 * p, r = u >> 2, c = u & 3;
            size_t g = (size_t)(rowTile + r) * 128 + kb + c * 8;
            *(uint4*)&U.s.Ahi[r * ASTRIDE + c * 8] = *(const uint4*)&Xhi[g];
            *(uint4*)&U.s.Alo[r * ASTRIDE + c * 8] = *(const uint4*)&Xlo[g];
        }
        #pragma unroll
        for (int p = 0; p < 2; ++p) {           // stage B (128 rows)
            int u = t + 256 * p, r = u >> 2, c = u & 3;
            size_t g = (size_t)(colTile + r) * 128 + kb + c * 8;
            *(uint4*)&U.s.Bhi[r * ASTRIDE + c * 8] = *(const uint4*)&Xhi[g];
            *(uint4*)&U.s.Blo[r * ASTRIDE + c * 8] = *(const uint4*)&Xlo[g];
        }
        __syncthreads();

        short8 a[4], bh[4], bl[4];
        #pragma unroll
        for (int i = 0; i < 4; ++i)
            a[i] = *(const short8*)&U.s.Ahi[(wr * 64 + 16 * i + lrow) * ASTRIDE + lkg * 8];
        #pragma unroll
        for (int j = 0; j < 4; ++j)
            bh[j] = *(const short8*)&U.s.Bhi[(wc * 64 + 16 * j + lrow) * ASTRIDE + lkg * 8];
        #pragma unroll
        for (int j = 0; j < 4; ++j)
            bl[j] = *(const short8*)&U.s.Blo[(wc * 64 + 16 * j + lrow) * ASTRIDE + lkg * 8];
        // pass 1: hi . hi
        #pragma unroll
        for (int i = 0; i < 4; ++i)
            #pragma unroll
            for (int j = 0; j < 4; ++j)
                acc[i][j] = __builtin_amdgcn_mfma_f32_16x16x32_bf16(a[i], bh[j], acc[i][j], 0, 0, 0);
        // pass 2: hi . lo
        #pragma unroll
        for (int i = 0; i < 4; ++i)
            #pragma unroll
            for (int j = 0; j < 4; ++j)
                acc[i][j] = __builtin_amdgcn_mfma_f32_16x16x32_bf16(a[i], bl[j], acc[i][j], 0, 0, 0);
        // pass 3: lo . hi (a reload; bh reused from regs)
        #pragma unroll
        for (int i = 0; i < 4; ++i)
            a[i] = *(const short8*)&U.s.Alo[(wr * 64 + 16 * i + lrow) * ASTRIDE + lkg * 8];
        #pragma unroll
        for (int i = 0; i < 4; ++i)
            #pragma unroll
            for (int j = 0; j < 4; ++j)
                acc[i][j] = __builtin_amdgcn_mfma_f32_16x16x32_bf16(a[i], bh[j], acc[i][j], 0, 0, 0);
    }

    // ---- epilogue: dual-pool LDS survivor aggregation, batched atomics ----
    __syncthreads();                            // staging LDS dead; overlay epilogue
    U.e.rc[t] = 0;
    __syncthreads();

    // C/D layout col=lane&15, row=(lane>>4)*4+reg  [m89/m91]
    float sqb[4], Tb[4]; int gcol[4], lcol[4];
    #pragma unroll
    for (int j = 0; j < 4; ++j) {
        lcol[j] = wc * 64 + 16 * j + lrow;
        gcol[j] = colTile + lcol[j];
        sqb[j]  = sqn[gcol[j]];
        Tb[j]   = Tthr[gcol[j]];
    }
    const int giBase = rowTile + wr * 64 + lkg * 4;
    float sav[4][4];                            // static-indexed, never address-taken
    #pragma unroll
    for (int i = 0; i < 4; ++i)
        #pragma unroll
        for (int q = 0; q < 4; ++q)
            sav[i][q] = sqn[giBase + 16 * i + q];

    float dall[4][4][4];                        // [i][q][j]; static-indexed only

    // forward: compute all 64 d once; one LDS atomic per (i,q) group
    #pragma unroll
    for (int i = 0; i < 4; ++i) {
        #pragma unroll
        for (int q = 0; q < 4; ++q) {
            const int gi = giBase + 16 * i + q;
            const int lr = gi - rowTile;
            const float Ti = Tthr[gi];
            unsigned m4 = 0;
            #pragma unroll
            for (int j = 0; j < 4; ++j) {
                float d = fmaxf(fmaf(-2.f, acc[i][j][q], sav[i][q] + sqb[j]), 0.f);
                dall[i][q][j] = d;
                bool c = (gcol[j] >= gi) && (d < Ti);
                m4 |= (unsigned)c << j;
            }
            if (m4) {
                unsigned o = atomicAdd(&U.e.rc[lr], (unsigned)__popc(m4));
                #pragma unroll
                for (int j = 0; j < 4; ++j)
                    if (m4 & (1u << j)) {
                        if (o < SLOTS)
                            U.e.slots[lr * SLOTS + o] = pack_key(dall[i][q][j], gcol[j]);
                        ++o;
                    }
            }
        }
    }
    // transpose: reuse dall; one LDS atomic per col j
    #pragma unroll
    for (int j = 0; j < 4; ++j) {
        const int pool = 128 + lcol[j];
        const float Tbj = Tb[j];
        const int gj = gcol[j];
        unsigned m16 = 0;
        #pragma unroll
        for (int i = 0; i < 4; ++i)
            #pragma unroll
            for (int q = 0; q < 4; ++q) {
                bool c = (gj > giBase + 16 * i + q) && (dall[i][q][j] < Tbj);
                m16 |= (unsigned)c << (i * 4 + q);
            }
        if (m16) {
            unsigned o = atomicAdd(&U.e.rc[pool], (unsigned)__popc(m16));
            #pragma unroll
            for (int i = 0; i < 4; ++i)
                #pragma unroll
                for (int q = 0; q < 4; ++q)
                    if (m16 & (1u << (i * 4 + q))) {
                        if (o < SLOTS)
                            U.e.slots[pool * SLOTS + o] =
                                pack_key(dall[i][q][j], giBase + 16 * i + q);
                        ++o;
                    }
        }
    }

    __syncthreads();
    {                                           // one global atomic per pool
        unsigned nr = U.e.rc[t];
        int grow = (t < 128) ? (rowTile + t) : (colTile + (t - 128));
        if (nr > SLOTS) {                       // ~never: force exact fallback
            atomicAdd(&cnt[grow], capb + 1);
            U.e.rbase[t] = 0xFFFFFFFFu;
        } else if (nr > 0) {
            U.e.rbase[t] = (unsigned)atomicAdd(&cnt[grow], (int)nr);
        } else {
            U.e.rbase[t] = 0;
        }
    }
    __syncthreads();
    #pragma unroll
    for (int it = 0; it < (256 * SLOTS) / 256; ++it) {   // coalesced flush
        int idx = t + 256 * it;
        int r = idx >> 4, s = idx & 15;
        unsigned nr = U.e.rc[r], base = U.e.rbase[r];
        if ((unsigned)s < min(nr, (unsigned)SLOTS) && base != 0xFFFFFFFFu) {
            unsigned pos = base + (unsigned)s;
            int grow = (r < 128) ? (rowTile + r) : (colTile + (r - 128));
            if (pos < (unsigned)capb)
                rowbuf[(size_t)grow * capb + pos] = U.e.slots[r * SLOTS + s];
        }
    }
}

// ---------------- K4: exact top-20 from survivor buffer (+ dual bitmap set) ----
__global__ __launch_bounds__(64) void k_sel2(const unsigned long long* __restrict__ rowbuf,
                                             const int* __restrict__ cnt,
                                             int* __restrict__ knn_idx,
                                             float* __restrict__ density,
                                             unsigned* __restrict__ bits,
                                             unsigned* __restrict__ bitsT,
                                             int* __restrict__ flagged,
                                             int* __restrict__ nflag, int capb) {
    __shared__ int nb[KNN];
    int row = blockIdx.x, t = threadIdx.x;
    int n = cnt[row];
    if (n < KNN || n > capb) {                  // model miss: exact fallback handles it
        if (t == 0) { int p = atomicAdd(nflag, 1); flagged[p] = row; }
        return;
    }
    const unsigned long long* rb = rowbuf + (size_t)row * capb;
    unsigned long long v[7];                    // 7*64 = 448 >= capb
    #pragma unroll
    for (int k = 0; k < 7; ++k) { int idx = t + 64 * k; v[k] = idx < n ? rb[idx] : ~0ull; }
    unsigned long long last = 0ull;
    float sumd = 0.f;
    for (int r = 0; r < KNN; ++r) {
        unsigned long long m = ~0ull;
        #pragma unroll
        for (int k = 0; k < 7; ++k) if (v[k] > last && v[k] < m) m = v[k];
        #pragma unroll
        for (int off = 32; off; off >>= 1) {
            unsigned long long o = __shfl_down(m, off, 64);
            if (o < m) m = o;
        }
        m = __shfl(m, 0, 64);
        last = m;
        if (t == 0) {
            int j = (int)(m & 16383ull) - 1;
            if (j < 0) j = 0; if (j >= N) j = N - 1;
            knn_idx[(size_t)row * KNN + r] = j;
            nb[r] = j;
            sumd += sqrtf(__uint_as_float((unsigned)(m >> 14)));
        }
    }
    if (t == 0) density[row] = 1.f / (sumd * (1.f / KNN) + EPS);
    __syncthreads();
    if (t < KNN) {
        int j = nb[t];
        atomicOr(&bits[(size_t)row * NW + (j >> 5)], 1u << (j & 31));
        atomicOr(&bitsT[(size_t)j * NW + (row >> 5)], 1u << (row & 31));  // fire-and-forget
    }
}

// ---------------- K4b: exact fp32 brute-force fallback for flagged rows -------
__global__ __launch_bounds__(256) void k_fallback(const float* __restrict__ X,
                                                  const float* __restrict__ sq,
                                                  const int* __restrict__ nflag,
                                                  const int* __restrict__ flagged,
                                                  int* __restrict__ knn_idx,
                                                  float* __restrict__ density,
                                                  unsigned* __restrict__ bits,
                                                  unsigned* __restrict__ bitsT) {
    __shared__ float xr[D];
    __shared__ unsigned long long red[256];
    __shared__ int nbf[KNN];
    int t = threadIdx.x;
    int nf = *nflag;
    for (int f = blockIdx.x; f < nf; f += gridDim.x) {
        int row = flagged[f];
        __syncthreads();
        if (t < D) xr[t] = X[(size_t)row * D + t];
        __syncthreads();
        float sqr = sq[row];
        unsigned long long keys[32];
        for (int i = 0; i < 32; ++i) {
            int col = t + 256 * i;
            const float4* cp = (const float4*)(X + (size_t)col * D);
            float dot = 0.f;
            #pragma unroll
            for (int d4 = 0; d4 < 32; ++d4) {
                float4 c = cp[d4];
                float4 x = *(const float4*)&xr[d4 * 4];
                dot = fmaf(c.x, x.x, dot); dot = fmaf(c.y, x.y, dot);
                dot = fmaf(c.z, x.z, dot); dot = fmaf(c.w, x.w, dot);
            }
            float d2v = fmaxf(sqr + sq[col] - 2.f * dot, 0.f);
            keys[i] = pack_key(d2v, col);
        }
        unsigned long long last = 0ull;
        float sumd = 0.f;
        for (int r = 0; r < KNN; ++r) {
            unsigned long long m = ~0ull;
            #pragma unroll
            for (int i = 0; i < 32; ++i) if (keys[i] > last && keys[i] < m) m = keys[i];
            red[t] = m; __syncthreads();
            for (int s = 128; s; s >>= 1) {
                if (t < s && red[t + s] < red[t]) red[t] = red[t + s];
                __syncthreads();
            }
            m = red[0]; __syncthreads();
            last = m;
            if (t == 0) {
                int j = (int)(m & 16383ull) - 1;
                if (j < 0) j = 0; if (j >= N) j = N - 1;
                knn_idx[(size_t)row * KNN + r] = j;
                nbf[r] = j;
                sumd += sqrtf(__uint_as_float((unsigned)(m >> 14)));
            }
        }
        if (t == 0) density[row] = 1.f / (sumd * (1.f / KNN) + EPS);
        __syncthreads();
        if (t < KNN) {
            int j = nbf[t];
            atomicOr(&bits[(size_t)row * NW + (j >> 5)], 1u << (j & 31));
            atomicOr(&bitsT[(size_t)j * NW + (row >> 5)], 1u << (row & 31));
        }
    }
}

// ---------------- K5: row-owned influence sums + final outputs (ZERO atomics) --
__global__ __launch_bounds__(256) void k_rev2(const int* __restrict__ knn_idx,
                                              const float* __restrict__ density,
                                              const unsigned* __restrict__ bits,
                                              const unsigned* __restrict__ bitsT,
                                              const float* __restrict__ logits,
                                              float* __restrict__ out) {
    int t = threadIdx.x & 63;
    int row = blockIdx.x * 4 + (threadIdx.x >> 6);
    float s = (t < KNN) ? density[knn_idx[(size_t)row * KNN + t]] : 0.f;
    int c = 0;
    const unsigned* br = bits  + (size_t)row * NW;
    const unsigned* tr = bitsT + (size_t)row * NW;
    #pragma unroll
    for (int w_ = 0; w_ < 4; ++w_) {
        int w = t + 64 * w_;
        unsigned u = tr[w] & ~br[w];
        c += __popc(u);
        while (u) {
            int b = __ffs(u) - 1;
            u &= u - 1;
            s += density[w * 32 + b];
        }
    }
    #pragma unroll
    for (int off = 32; off; off >>= 1) {
        s += __shfl_down(s, off, 64);
        c += __shfl_down(c, off, 64);
    }
    if (t == 0) {
        float cf    = fmaxf((float)(KNN + c), 1.f);
        float avg   = s / cf;
        float dens  = density[row];
        float score = -(dens / (avg + EPS));
        out[row] = score;
        bool flag = score < -0.5f;
        out[N + row] = flag ? 1.f : 0.f;
        const float* lg = logits + (size_t)row * NC;
        float best = lg[0]; int bi = 0;
        #pragma unroll
        for (int k = 1; k < NC; ++k) { float x = lg[k]; if (x > best) { best = x; bi = k; } }
        out[2 * N + row] = flag ? -1.f : (float)bi;
    }
}

extern "C" void kernel_launch(void* const* d_in, const int* in_sizes, int n_in,
                              void* d_out, int out_size, void* d_ws, size_t ws_size,
                              hipStream_t stream) {
    const float* X      = (const float*)d_in[0];
    const float* logits = (const float*)d_in[1];
    float* out = (float*)d_out;

    char* w = (char*)d_ws;
    auto alloc = [&](size_t bytes) { char* p = w; w += (bytes + 255) & ~(size_t)255; return p; };
    float* sq      = (float*)alloc((size_t)N * 4);
    float* density = (float*)alloc((size_t)N * 4);
    int*   knn     = (int*)alloc((size_t)N * KNN * 4);
    unsigned short* Xhi = (unsigned short*)alloc((size_t)N * D * 2);
    unsigned short* Xlo = (unsigned short*)alloc((size_t)N * D * 2);
    float* Tthr    = (float*)alloc((size_t)N * 4);
    int*   flagged = (int*)alloc((size_t)N * 4);
    // contiguous zero region (zeroed by k_prep): cnt + nflag + m1
    char* zbase    = w;
    int*   cnt     = (int*)alloc((size_t)N * 4);
    int*   nflag   = (int*)alloc(256);
    float* m1      = (float*)alloc((size_t)(D + 2) * 4);
    int nzw = (int)((size_t)(w - zbase) / 4);   // ~8.5K words << 512K prep threads
    unsigned* bits  = (unsigned*)alloc((size_t)N * NW * 4);   // 8 MB forward bitmap
    unsigned* bitsT = (unsigned*)alloc((size_t)N * NW * 4);   // 8 MB transpose bitmap

    size_t used  = (size_t)(w - (char*)d_ws);
    size_t avail = ws_size > used ? ws_size - used : 0;
    int capb = (int)(avail / ((size_t)N * 8));
    if (capb > CAPB) capb = CAPB;
    if (capb < 1) capb = 1;                     // degenerate: all rows -> exact fallback
    unsigned long long* rowbuf = (unsigned long long*)alloc((size_t)N * capb * 8);

    k_prep   <<<N, 64, 0, stream>>>(X, Xhi, Xlo, sq, (uint4*)bits, (uint4*)bitsT,
                                    (unsigned*)zbase, nzw);
    k_moments<<<512, 128, 0, stream>>>(X, sq, m1, m1 + D);
    k_thresh <<<N, 64, 0, stream>>>(X, sq, m1, m1 + D, Tthr);

    k_distf3 <<<NBLK, 256, 0, stream>>>(Xhi, Xlo, sq, Tthr, cnt, rowbuf, capb);

    k_sel2    <<<N, 64, 0, stream>>>(rowbuf, cnt, knn, density, bits, bitsT,
                                     flagged, nflag, capb);
    k_fallback<<<64, 256, 0, stream>>>(X, sq, nflag, flagged, knn, density, bits, bitsT);

    k_rev2   <<<N / 4, 256, 0, stream>>>(knn, density, bits, bitsT, logits, out);
}